// Round 7
// baseline (229.683 us; speedup 1.0000x reference)
//
#include <hip/hip_runtime.h>

// NCC forces, 192^3 fp32. Round 11: R10 (512-thr / 32x16 tile) with the
// T-field pitch bug fixed.
// R10 post-mortem: correctness fail was Tf declared [.][.][32] while emit
// reads cols up to tx+3=34 (and x-phase only wrote 32 of the 36 needed
// cols). T col c <-> raw local c+2, c=0..35 -> pitch TW=TSX+4=36, with
// chunk t4==28 writing the extra cols 32..35 from a[6..9].
// Schedule unchanged from R8 (2 barriers), geometry from R10:
//   x: 160 lanes (2.5 waves), y: 320 lanes (5 waves), emit: 8 waves.
//   LDS 50048 B -> 3 blocks/CU = 24-wave ceiling (was 11 waves resident).
//   Halo amp 1.875x -> 1.5625x in-plane (FETCH ~-10%).

#define DD 192
#define HH 192
#define WW 192
#define NVOX (DD * HH * WW)
#define SLICE (HH * WW)
#define TSX 32
#define TSY 16
#define TW (TSX + 4)     // T-field pitch: cols 0..35 <-> raw local 2..37
#define RR 20            // staged rows (y: y0-2 .. y0+17)
#define RW 40            // staged row width (x: x0-4 .. x0+35)
#define ZSEG 12
#define NBX 6
#define NBY 12
#define NBZ 16
#define NBLK (NBX * NBY * NBZ)        // 1152
#define PER_XCD (NBLK / 8)            // 144

__global__ __launch_bounds__(512)
void ncc_forces_kernel(const float* __restrict__ mimg,
                       const float* __restrict__ fimg,
                       const int*   __restrict__ mmask,
                       const int*   __restrict__ fmask,
                       float* __restrict__ out)
{
    __shared__ float rawm[RR][RW];         // 3200 B (single slot)
    __shared__ float rawf[RR][RW];         // 3200 B
    __shared__ float xs[5][RR][TSX];       // 12800 B [field][yrow][xo]
    __shared__ float Tf[4][18][TW];        // 10368 B (m+f); stored row r <-> raw row r+1
    __shared__ float box[2][TSX][5][TSY];  // 20480 B [pp][x][field][yout]
    // total 50048 B -> 3 blocks/CU = 24 waves

    // XCD swizzle: XCD k gets 144 consecutive logical blocks
    const int b  = blockIdx.x;
    const int L  = (b & 7) * PER_XCD + (b >> 3);
    const int bz = L / (NBX * NBY);
    const int r_ = L - bz * (NBX * NBY);
    const int by = r_ / NBX;
    const int bx = r_ - by * NBX;

    const int tid = threadIdx.x;
    const int tx = tid & 31, ty = tid >> 5;
    const int x0 = bx * TSX, y0 = by * TSY, z0 = bz * ZSEG;

    // ---- staging roles: 400 lanes = 2 images x 20 rows x 10 quads ----
    const int  simg   = tid / 200;            // 0,1 stager; 2 idle
    const bool stager = (simg < 2);
    const int  st     = tid - simg * 200;
    const int  srow   = st / 10;
    const int  squad  = st - srow * 10;
    const int  sgy    = y0 - 2 + srow;
    const int  sgx    = x0 - 4 + 4 * squad;   // quads all-in or all-out (x0%32==0)
    const bool sin_   = (sgy >= 0) && (sgy < HH) && (sgx >= 0) && (sgx <= WW - 4);
    const float* sptr = (simg == 1) ? fimg : mimg;
    float* sldsb = (simg == 1) ? &rawf[0][0] : &rawm[0][0];
    const int  sloff  = srow * RW + 4 * squad;

    float4 pref = make_float4(0, 0, 0, 0);
    auto prefetch = [&](int zz) {
        pref = make_float4(0, 0, 0, 0);
        if (stager && sin_ && zz >= 0 && zz < DD)
            pref = *(const float4*)(sptr + ((size_t)zz * HH + sgy) * WW + sgx);
    };

    // per-thread rings
    float ring[5][5];
#pragma unroll
    for (int s = 0; s < 5; ++s)
#pragma unroll
        for (int f = 0; f < 5; ++f) ring[s][f] = 0.f;
    float cm[5] = {0, 0, 0, 0, 0}, cf[5] = {0, 0, 0, 0, 0};

    const int gx = x0 + tx, gy = y0 + ty;
    const int vbase = (z0 * HH + gy) * WW + gx;   // voxel index at z=z0
    int umN = 0, ufN = 0;                          // masks prefetched 1 iter ahead

    prefetch(z0 - 2);

    for (int n = 0; n <= ZSEG + 4; ++n) {
        const int zc = z0 - 2 + n;           // slice committed this iter
        const int z  = zc - 3;               // slice emitted this iter
        const bool emitv = (n >= 5);

        // ---- commit staged slice zc; issue loads for zc+1 ----
        // WAR vs iter-(n-1)'s raw reads is fenced by barrier B of iter n-1.
        if (stager) *(float4*)(sldsb + sloff) = pref;
        prefetch(zc + 1);

        const int um = umN, uf = ufN;        // masks for THIS iter's emit
        if (n >= 4 && n < ZSEG + 4) {        // prefetch for iter n+1
            const int vn = vbase + (n - 4) * SLICE;
            umN = __builtin_nontemporal_load(mmask + vn);
            ufN = __builtin_nontemporal_load(fmask + vn);
        }

        __syncthreads();   // A: raw ready; box[(n-1)&1] (y of n-1) ready

        // ---- x-phase: 160 chunk-of-4 tasks; also emits T = m+f ----
        if (tid < 160) {
            const int yy = tid >> 3;          // 0..19
            const int t4 = (tid & 7) * 4;     // 0,4,...,28
            const float4 A0 = *(const float4*)&rawm[yy][t4];
            const float4 A1 = *(const float4*)&rawm[yy][t4 + 4];
            const float2 A2 = *(const float2*)&rawm[yy][t4 + 8];
            const float4 B0 = *(const float4*)&rawf[yy][t4];
            const float4 B1 = *(const float4*)&rawf[yy][t4 + 4];
            const float2 B2 = *(const float2*)&rawf[yy][t4 + 8];
            const float a[10]  = {A0.x, A0.y, A0.z, A0.w, A1.x, A1.y, A1.z, A1.w, A2.x, A2.y};
            const float bb[10] = {B0.x, B0.y, B0.z, B0.w, B1.x, B1.y, B1.z, B1.w, B2.x, B2.y};
            float p[10], s, w0, w1, w2, w3;
#pragma unroll
            for (int f = 0; f < 5; ++f) {
#pragma unroll
                for (int i = 2; i < 10; ++i) {
                    p[i] = (f == 0) ? a[i] : (f == 1) ? bb[i] :
                           (f == 2) ? a[i] * a[i] : (f == 3) ? bb[i] * bb[i] : a[i] * bb[i];
                }
                s = p[2] + p[3] + p[4] + p[5] + p[6]; w0 = s;
                s += p[7] - p[2]; w1 = s;
                s += p[8] - p[3]; w2 = s;
                s += p[9] - p[4]; w3 = s;
                *(float4*)&xs[f][yy][t4] = make_float4(w0, w1, w2, w3);
            }
            // T col c = raw local c+2, c = 0..35; rows 1..18 only
            if (yy >= 1 && yy <= 18) {
                const int tw = n & 3;
                *(float4*)&Tf[tw][yy - 1][t4] =
                    make_float4(a[2] + bb[2], a[3] + bb[3], a[4] + bb[4], a[5] + bb[5]);
                if (t4 == 28)   // cols 32..35 from raw 34..37
                    *(float4*)&Tf[tw][yy - 1][32] =
                        make_float4(a[6] + bb[6], a[7] + bb[7], a[8] + bb[8], a[9] + bb[9]);
            }
        }

        // ---- centers: fresh slice zc -> register ring ----
        {
            const float ncm = rawm[ty + 2][tx + 4];
            const float ncf = rawf[ty + 2][tx + 4];
#pragma unroll
            for (int s2 = 4; s2 > 0; --s2) { cm[s2] = cm[s2 - 1]; cf[s2] = cf[s2 - 1]; }
            cm[0] = ncm; cf[0] = ncf;
        }
        // 2D sums of slice zc-1 (y-phase of iter n-1) -> ring
        if (n >= 1) {
            const float* bq = &box[(n - 1) & 1][tx][0][ty];   // f-stride 16 dwords
            const float s0 = bq[0], s1 = bq[16], s2v = bq[32], s3 = bq[48], s4 = bq[64];
#pragma unroll
            for (int s = 0; s < 4; ++s)
#pragma unroll
                for (int f = 0; f < 5; ++f) ring[s][f] = ring[s + 1][f];
            ring[4][0] = s0; ring[4][1] = s1; ring[4][2] = s2v; ring[4][3] = s3; ring[4][4] = s4;
        }

        if (emitv) {
            float sum_m = 0.f, sum_f = 0.f, sum_mm = 0.f, sum_ff = 0.f, sum_mf = 0.f;
#pragma unroll
            for (int s = 0; s < 5; ++s) {
                sum_m  += ring[s][0];
                sum_f  += ring[s][1];
                sum_mm += ring[s][2];
                sum_ff += ring[s][3];
                sum_mf += ring[s][4];
            }
            const int vidx = vbase + (n - 5) * SLICE;
            const int tsl  = (n + 1) & 3;     // T slot of slice z (written iter n-3)
            const float mc = cm[3];           // center at z
            const float fc = cf[3];
            const float Tc = mc + fc;

            // gradient sums via T field (stored row r <-> raw row r+1,
            // stored col c <-> raw col c+2 <-> global x0+c-2)
            const float* tp = &Tf[tsl][ty + 1][tx + 1];   // {gx-1, gx+1}: offs 0, 2
            const float Txm = tp[0], Txp = tp[2];
            const float* tq = &Tf[tsl][ty][tx + 2];       // {gy-1, gy+1}: offs 0, 2*TW
            const float Tym = tq[0], Typ = tq[2 * TW];

            float gsx, gsy, gsz;
            if (gx == 0)          gsx = Txp - Tc;
            else if (gx == WW-1)  gsx = Tc - Txm;
            else                  gsx = 0.5f * (Txp - Txm);
            if (gy == 0)          gsy = Typ - Tc;
            else if (gy == HH-1)  gsy = Tc - Tym;
            else                  gsy = 0.5f * (Typ - Tym);
            const float Tzm = cm[4] + cf[4], Tzp = cm[2] + cf[2];
            if (z == 0)           gsz = Tzp - Tc;
            else if (z == DD-1)   gsz = Tc - Tzm;
            else                  gsz = 0.5f * (Tzp - Tzm);

            const float u = ((um != 0) || (uf != 0)) ? 1.0f : 0.0f;

            const float npix = 125.0f;
            const float inv_npix = 1.0f / 125.0f;
            const float mean_m = sum_m * inv_npix;
            const float mean_f = sum_f * inv_npix;
            const float var_m = sum_mm - 2.0f * mean_m * sum_m + npix * mean_m * mean_m;
            const float var_f = sum_ff - 2.0f * mean_f * sum_f + npix * mean_f * mean_f;
            const float var_mf = var_m * var_f;
            const float cross = sum_mf - mean_f * sum_m - mean_m * sum_f + npix * mean_m * mean_f;
            const float mmc = mc - mean_m;
            const float fmc = fc - mean_f;
            const bool ok = (var_mf > 1e-5f) && (var_f > 1e-5f) && (fmc != 0.0f) && (mmc != 0.0f);
            float factor = 0.0f;
            if (ok) factor = 2.0f * cross / var_mf * (mmc - cross * fmc / var_f);

            const float nf = -factor * 0.5f * u;
            out[vidx]            = nf * gsz;   // ch 0: d/dD
            out[NVOX + vidx]     = nf * gsy;   // ch 1: d/dH
            out[2 * NVOX + vidx] = nf * gsx;   // ch 2: d/dW
        }

        __syncthreads();   // B: xs/Tf ready; emit/x/centers reads of raw done

        // ---- y-phase: 320 chunk-of-8 sliding tasks -> box[n&1] ----
        if (tid >= 192) {
            const int ytid = tid - 192;            // 0..319
            const int x  = ytid & 31;
            const int c8 = ((ytid >> 5) & 1) * 8;  // 0 or 8
            const int f  = ytid >> 6;              // 0..4
            const float* xp = &xs[f][c8][x];       // row stride 32 dwords
            float v[12];
#pragma unroll
            for (int j = 0; j < 12; ++j) v[j] = xp[32 * j];
            float o[8];
            float s = v[0] + v[1] + v[2] + v[3] + v[4];
            o[0] = s;
#pragma unroll
            for (int j = 1; j < 8; ++j) { s += v[j + 4] - v[j - 1]; o[j] = s; }
            float* bp = &box[n & 1][x][f][c8];
            *(float4*)bp       = make_float4(o[0], o[1], o[2], o[3]);
            *(float4*)(bp + 4) = make_float4(o[4], o[5], o[6], o[7]);
        }
        // no trailing barrier:
        //  - commit(n+1) writes raw after B(n); iter-n raw reads were pre-B.
        //  - next x-phase (writes xs/Tf[(n+1)&3]) is fenced by next barrier A;
        //    Tf[(n+1)&3] was last read at emit(n) before B(n).
        //  - box[n&1] is read at ingest(n+1) after A(n+1), rewritten at y(n+2).
    }
}

extern "C" void kernel_launch(void* const* d_in, const int* in_sizes, int n_in,
                              void* d_out, int out_size, void* d_ws, size_t ws_size,
                              hipStream_t stream)
{
    const float* mimg  = (const float*)d_in[0];
    const float* fimg  = (const float*)d_in[1];
    const int*   mmask = (const int*)d_in[2];
    const int*   fmask = (const int*)d_in[3];
    float* out = (float*)d_out;

    dim3 grid(NBLK, 1, 1);   // 1152 blocks
    dim3 block(512, 1, 1);
    hipLaunchKernelGGL(ncc_forces_kernel, grid, block, 0, stream,
                       mimg, fimg, mmask, fmask, out);
}

// Round 8
// 218.705 us; speedup vs baseline: 1.0502x; 1.0502x over previous
//
#include <hip/hip_runtime.h>

// NCC forces, 192^3 fp32. Round 12: barrier-free 1-wave workgroups.
// R8-R11 ledger: LDS instr diet X, bank conflicts X (R9 cut 25%, time up),
// LDS capacity X (cap 4->5 flat), barrier count X (R9 1-barrier worse),
// HBM X (23%). Occupancy pinned ~11 waves/CU across caps 16/20/24 ->
// multi-wave blocks sit convoyed at __syncthreads. This round: each wave
// owns a 16x4xZSEG tile and does stage/x-sum/y-sum/grad/emit itself.
// __syncthreads in a 1-wave block = intra-wave fence (near-free); all
// 6912 waves are independent -> scheduler can actually hide latency.
//  - S2D z-ring slot-static via 4x5 unrolled z-loop (no runtime idx).
//  - gradients computed at slice time, held in 3-deep register rings.
//  - LDS 4.1KB/block; __launch_bounds__(64,4) caps VGPR at 128.
//  - Cost: 3x in-plane staging amp (L2/L3-absorbed; inputs L3-resident).

#define DD 192
#define HH 192
#define WW 192
#define NVOX (DD * HH * WW)
#define SLICE (HH * WW)
#define TSX 16
#define TSY 4
#define SR 8             // staged rows: y0-2 .. y0+5
#define SC 24            // staged cols: x0-4 .. x0+19
#define ZSEG 16
#define NBX 12           // 192/16
#define NBY 48           // 192/4
#define NBZ 12           // 192/16
#define NBLK (NBX * NBY * NBZ)        // 6912
#define PER_XCD (NBLK / 8)            // 864

__global__ __launch_bounds__(64, 4)
void ncc_forces_kernel(const float* __restrict__ mimg,
                       const float* __restrict__ fimg,
                       const int*   __restrict__ mmask,
                       const int*   __restrict__ fmask,
                       float* __restrict__ out)
{
    __shared__ float rawm[SR][SC];     // 768 B
    __shared__ float rawf[SR][SC];     // 768 B
    __shared__ float xs[5][SR][TSX];   // 2560 B [field][srow][outcol]
    // total 4096 B -> LDS not binding

    // XCD swizzle: XCD k gets 864 consecutive logical blocks
    const int b  = blockIdx.x;
    const int L  = (b & 7) * PER_XCD + (b >> 3);
    const int bz = L / (NBX * NBY);
    const int r_ = L - bz * (NBX * NBY);
    const int by = r_ / NBX;
    const int bx = r_ - by * NBX;

    const int lane = threadIdx.x;
    const int tx = lane & 15, ty = lane >> 4;          // voxel within tile
    const int xr = lane >> 3, xo = lane & 7;           // x-phase role: row, col-pair
    const int x0 = bx * TSX, y0 = by * TSY, z0 = bz * ZSEG;

    // ---- staging roles: 96 quads (2 images x 8 rows x 6 quads), 2 rounds ----
    // round1 (all 64): m quads 0..47 (lanes 0-47) + f quads 0..15 (lanes 48-63)
    // round2 (lanes 0-31): f quads 16..47
    const int  q1    = (lane < 48) ? lane : (lane - 48);
    const bool img1f = (lane >= 48);
    const int  r1q   = q1 / 6, c1q = (q1 - r1q * 6) * 4;
    const int  q2    = 16 + lane;
    const int  r2q   = q2 / 6, c2q = (q2 - r2q * 6) * 4;
    const int  sgy1  = y0 - 2 + r1q, sgx1 = x0 - 4 + c1q;
    const int  sgy2  = y0 - 2 + r2q, sgx2 = x0 - 4 + c2q;
    const bool in1   = (sgy1 >= 0) && (sgy1 < HH) && (sgx1 >= 0) && (sgx1 <= WW - 4);
    const bool in2   = (lane < 32) && (sgy2 >= 0) && (sgy2 < HH) && (sgx2 >= 0) && (sgx2 <= WW - 4);
    const float* sp1 = img1f ? fimg : mimg;
    float* sd1 = img1f ? &rawf[0][0] : &rawm[0][0];
    const int so1 = r1q * SC + c1q;
    const int so2 = r2q * SC + c2q;

    float4 A = make_float4(0, 0, 0, 0), Bv = make_float4(0, 0, 0, 0);
    auto prefetch = [&](int zz, bool en) {
        A = make_float4(0, 0, 0, 0); Bv = make_float4(0, 0, 0, 0);
        if (en && zz >= 0 && zz < DD) {
            if (in1) A  = *(const float4*)(sp1  + ((size_t)zz * HH + sgy1) * WW + sgx1);
            if (in2) Bv = *(const float4*)(fimg + ((size_t)zz * HH + sgy2) * WW + sgx2);
        }
    };

    // per-lane state (all static-indexed -> registers)
    float ring[5][5];                      // S2D z-window, slot = n%5 (static via unroll)
#pragma unroll
    for (int sl = 0; sl < 5; ++sl)
#pragma unroll
        for (int f = 0; f < 5; ++f) ring[sl][f] = 0.f;
    float cm[4] = {0, 0, 0, 0}, cf[4] = {0, 0, 0, 0};   // centers: slices s..s-3
    float gsxr[3] = {0, 0, 0}, gsyr[3] = {0, 0, 0};     // grad sums: slices s..s-2
    int umC = 0, ufC = 0, umN = 0, ufN = 0;

    const int gx = x0 + tx, gy = y0 + ty;

    prefetch(z0 - 2, true);

    for (int no = 0; no < 4; ++no) {
#pragma unroll
        for (int ni = 0; ni < 5; ++ni) {
            const int n = no * 5 + ni;           // 0..19
            const int s = z0 - 2 + n;            // slice staged+processed this iter

            // ---- commit staged slice s; prefetch s+1 ----
            *(float4*)(sd1 + so1) = A;
            if (lane < 32) *(float4*)(&rawf[0][0] + so2) = Bv;
            prefetch(s + 1, n < ZSEG + 3);

            // ---- mask rotate + prefetch for next iter's emit (z' = z0-3+n) ----
            umC = umN; ufC = ufN;
            if (n >= 3 && n <= ZSEG + 2) {
                const size_t vq = ((size_t)(z0 - 3 + n) * HH + gy) * WW + gx;
                umN = __builtin_nontemporal_load(mmask + vq);
                ufN = __builtin_nontemporal_load(fmask + vq);
            }

            __syncthreads();   // 1-wave block: intra-wave fence, raw visible

            // ---- centers + gradients for slice s -> register rings ----
            {
                const float ncm = rawm[ty + 2][tx + 4];
                const float ncf = rawf[ty + 2][tx + 4];
                const float Txm = rawm[ty + 2][tx + 3] + rawf[ty + 2][tx + 3];
                const float Txp = rawm[ty + 2][tx + 5] + rawf[ty + 2][tx + 5];
                const float Tym = rawm[ty + 1][tx + 4] + rawf[ty + 1][tx + 4];
                const float Typ = rawm[ty + 3][tx + 4] + rawf[ty + 3][tx + 4];
                const float Tc  = ncm + ncf;
                const float ngsx = (gx == 0) ? (Txp - Tc) :
                                   (gx == WW - 1) ? (Tc - Txm) : 0.5f * (Txp - Txm);
                const float ngsy = (gy == 0) ? (Typ - Tc) :
                                   (gy == HH - 1) ? (Tc - Tym) : 0.5f * (Typ - Tym);
                gsxr[2] = gsxr[1]; gsxr[1] = gsxr[0]; gsxr[0] = ngsx;
                gsyr[2] = gsyr[1]; gsyr[1] = gsyr[0]; gsyr[0] = ngsy;
                cm[3] = cm[2]; cm[2] = cm[1]; cm[1] = cm[0]; cm[0] = ncm;
                cf[3] = cf[2]; cf[2] = cf[1]; cf[1] = cf[0]; cf[0] = ncf;
            }

            // ---- x-phase: row xr, out-cols 2xo..2xo+1 (staged cols 2xo+2..2xo+7) ----
            {
                const float2 M0 = *(const float2*)&rawm[xr][2 * xo + 2];
                const float2 M1 = *(const float2*)&rawm[xr][2 * xo + 4];
                const float2 M2 = *(const float2*)&rawm[xr][2 * xo + 6];
                const float2 F0 = *(const float2*)&rawf[xr][2 * xo + 2];
                const float2 F1 = *(const float2*)&rawf[xr][2 * xo + 4];
                const float2 F2 = *(const float2*)&rawf[xr][2 * xo + 6];
                const float m6[6] = {M0.x, M0.y, M1.x, M1.y, M2.x, M2.y};
                const float f6[6] = {F0.x, F0.y, F1.x, F1.y, F2.x, F2.y};
#pragma unroll
                for (int f = 0; f < 5; ++f) {
                    float v[6];
#pragma unroll
                    for (int i = 0; i < 6; ++i)
                        v[i] = (f == 0) ? m6[i] : (f == 1) ? f6[i] :
                               (f == 2) ? m6[i] * m6[i] : (f == 3) ? f6[i] * f6[i]
                                        : m6[i] * f6[i];
                    const float X0 = v[0] + v[1] + v[2] + v[3] + v[4];
                    const float X1 = X0 + v[5] - v[0];
                    *(float2*)&xs[f][xr][2 * xo] = make_float2(X0, X1);
                }
            }

            __syncthreads();   // intra-wave fence, xs visible

            // ---- y-sum: S2D for (tx,ty) at slice s -> ring[ni] (static slot) ----
#pragma unroll
            for (int f = 0; f < 5; ++f)
                ring[ni][f] = xs[f][ty][tx] + xs[f][ty + 1][tx] + xs[f][ty + 2][tx]
                            + xs[f][ty + 3][tx] + xs[f][ty + 4][tx];

            // ---- emit z = s-2 = z0-4+n (ring holds slices s-4..s) ----
            if (n >= 4) {
                float sum_m = 0.f, sum_f = 0.f, sum_mm = 0.f, sum_ff = 0.f, sum_mf = 0.f;
#pragma unroll
                for (int sl = 0; sl < 5; ++sl) {
                    sum_m  += ring[sl][0];
                    sum_f  += ring[sl][1];
                    sum_mm += ring[sl][2];
                    sum_ff += ring[sl][3];
                    sum_mf += ring[sl][4];
                }
                const int z = z0 - 4 + n;
                const size_t vidx = ((size_t)z * HH + gy) * WW + gx;
                const float mc = cm[2];          // center at z
                const float fc = cf[2];
                const float Tc = mc + fc;
                const float Tzp = cm[1] + cf[1]; // z+1
                const float Tzm = cm[3] + cf[3]; // z-1
                float gsz;
                if (z == 0)           gsz = Tzp - Tc;
                else if (z == DD - 1) gsz = Tc - Tzm;
                else                  gsz = 0.5f * (Tzp - Tzm);
                const float gsx = gsxr[2], gsy = gsyr[2];

                const float u = ((umC != 0) || (ufC != 0)) ? 1.0f : 0.0f;

                const float npix = 125.0f;
                const float inv_npix = 1.0f / 125.0f;
                const float mean_m = sum_m * inv_npix;
                const float mean_f = sum_f * inv_npix;
                const float var_m = sum_mm - 2.0f * mean_m * sum_m + npix * mean_m * mean_m;
                const float var_f = sum_ff - 2.0f * mean_f * sum_f + npix * mean_f * mean_f;
                const float var_mf = var_m * var_f;
                const float cross = sum_mf - mean_f * sum_m - mean_m * sum_f
                                  + npix * mean_m * mean_f;
                const float mmc = mc - mean_m;
                const float fmc = fc - mean_f;
                const bool ok = (var_mf > 1e-5f) && (var_f > 1e-5f) &&
                                (fmc != 0.0f) && (mmc != 0.0f);
                float factor = 0.0f;
                if (ok) factor = 2.0f * cross / var_mf * (mmc - cross * fmc / var_f);

                const float nf = -factor * 0.5f * u;
                out[vidx]            = nf * gsz;   // ch 0: d/dD
                out[NVOX + vidx]     = nf * gsy;   // ch 1: d/dH
                out[2 * NVOX + vidx] = nf * gsx;   // ch 2: d/dW
            }
            // WAR on raw/xs across iters: same wave, in-order LDS -> safe.
        }
    }
}

extern "C" void kernel_launch(void* const* d_in, const int* in_sizes, int n_in,
                              void* d_out, int out_size, void* d_ws, size_t ws_size,
                              hipStream_t stream)
{
    const float* mimg  = (const float*)d_in[0];
    const float* fimg  = (const float*)d_in[1];
    const int*   mmask = (const int*)d_in[2];
    const int*   fmask = (const int*)d_in[3];
    float* out = (float*)d_out;

    dim3 grid(NBLK, 1, 1);   // 6912 one-wave blocks
    dim3 block(64, 1, 1);
    hipLaunchKernelGGL(ncc_forces_kernel, grid, block, 0, stream,
                       mimg, fimg, mmask, fmask, out);
}